// Round 7
// baseline (265.289 us; speedup 1.0000x reference)
//
#include <hip/hip_runtime.h>
#include <math.h>
#include <stdint.h>

#define NB 16
#define NH 512
#define NW 512
#define PLANE (NH * NW)
#define INF_D 1.0e9f
#define INF2 1.0e18f   // == fl(1e9f*1e9f), matches reference d*d rounding
#define BIG 3.0e38f
#define NSEG 64        // 512 / 8
#define TWB 8          // tile width (cols per block)
#define HROW 516       // LDS row stride (floats)
#define NBLK 1024
#define NTHR 512

// ---------------------------------------------------------------------------
// Device-scope grid barrier (persistent-kernel style). All NBLK blocks are
// provably co-resident: 512 thr + launch_bounds(512,8) forces VGPR<=64 ->
// 4 blocks/CU by waves (32/CU) and LDS (22.7KB*4=90.6KB<160KB); 5 blocks
// can't fit (40 waves > 32), so 1024 blocks land exactly 4/CU on 256 CUs.
// __threadfence release/acquire emits cross-XCD L2 writeback/invalidate.
// ctr/flag zeroed by hipMemsetAsync before each launch (replay-safe).
// ---------------------------------------------------------------------------
__device__ __forceinline__ void grid_barrier(unsigned int* ctr,
                                             unsigned int* flag) {
    __syncthreads();
    if (threadIdx.x == 0) {
        __threadfence();  // release: make this block's writes visible (L2 wb)
        unsigned int prev = __hip_atomic_fetch_add(ctr, 1u, __ATOMIC_ACQ_REL,
                                                   __HIP_MEMORY_SCOPE_AGENT);
        if (prev == NBLK - 1) {
            __hip_atomic_store(flag, 1u, __ATOMIC_RELEASE,
                               __HIP_MEMORY_SCOPE_AGENT);
        } else {
            while (__hip_atomic_load(flag, __ATOMIC_ACQUIRE,
                                     __HIP_MEMORY_SCOPE_AGENT) == 0u) {
                __builtin_amdgcn_s_sleep(2);
            }
        }
        __threadfence();  // acquire: invalidate stale L1/L2 before reads
    }
    __syncthreads();
}

// ---------------------------------------------------------------------------
// Ring-pruned exact min-plus over one LDS row (h = g + k^2, stride HROW).
// best[j] = min_k(h[k] - 2*i_j*k); true value = i_j^2 + best[j] (exact ints
// < 2^24 on the finite path -> bit-exact; INF2 absorbs k^2 shifts).
// smin has stride TWB (8) per segment.
// ---------------------------------------------------------------------------
__device__ __forceinline__ void eval_minplus(const float* __restrict__ hrow,
                                             const float* __restrict__ sminw,
                                             int q, float* best,
                                             const float* neg2i,
                                             const float* ifl) {
    float bmax = BIG;
    for (int step = 0; step < 2 * NSEG - 1; ++step) {
        int r = (step + 1) >> 1;
        float gapf = (float)(8 * (r - 1) + 1);
        float gap2 = gapf * gapf;
        if ((step & 1) && gap2 >= bmax) break;
        int s = (step & 1) ? (q - r) : (q + r);
        if (s < 0 || s >= NSEG) continue;
        if (step && (gap2 + sminw[s * TWB] >= bmax)) continue;
        const float* hp = hrow + s * 8;
        float4 A = *reinterpret_cast<const float4*>(hp);
        float4 B = *reinterpret_cast<const float4*>(hp + 4);
        float s8f = (float)(s * 8);
#pragma unroll
        for (int j = 0; j < 8; ++j) {
            float n2 = neg2i[j];
            float c0 = fmaf(n2, s8f, A.x);
            float c1 = fmaf(n2, s8f + 1.0f, A.y);
            float c2 = fmaf(n2, s8f + 2.0f, A.z);
            float c3 = fmaf(n2, s8f + 3.0f, A.w);
            float c4 = fmaf(n2, s8f + 4.0f, B.x);
            float c5 = fmaf(n2, s8f + 5.0f, B.y);
            float c6 = fmaf(n2, s8f + 6.0f, B.z);
            float c7 = fmaf(n2, s8f + 7.0f, B.w);
            float bb = fminf(fminf(best[j], c0), c1);
            bb = fminf(fminf(bb, c2), c3);
            bb = fminf(fminf(bb, c4), c5);
            bb = fminf(fminf(bb, c6), c7);
            best[j] = bb;
        }
        float t0 = fmaf(ifl[0], ifl[0], best[0]);
        float t1 = fmaf(ifl[1], ifl[1], best[1]);
        float t2 = fmaf(ifl[2], ifl[2], best[2]);
        float t3 = fmaf(ifl[3], ifl[3], best[3]);
        float t4 = fmaf(ifl[4], ifl[4], best[4]);
        float t5 = fmaf(ifl[5], ifl[5], best[5]);
        float t6 = fmaf(ifl[6], ifl[6], best[6]);
        float t7 = fmaf(ifl[7], ifl[7], best[7]);
        float m = fmaxf(fmaxf(t0, t1), t2);
        m = fmaxf(fmaxf(m, t3), t4);
        m = fmaxf(fmaxf(m, t5), t6);
        bmax = fmaxf(m, t7);
    }
}

// ---------------------------------------------------------------------------
// Fused persistent kernel: A (B-scan -> u8 codes), barrier, B (H min-plus,
// +w^2 folded, NaN flag in sign bit), barrier, C (W min-plus in-place,
// sqrt + NaN). 1024 blocks x 512 threads.
// ---------------------------------------------------------------------------
__global__ __launch_bounds__(NTHR, 8) void k_fused(const float* __restrict__ x,
                                                   float* __restrict__ out,
                                                   unsigned char* __restrict__ code,
                                                   unsigned int* __restrict__ bar) {
    __shared__ float hs[TWB * HROW];        // 16.5 KB
    __shared__ float smin[NSEG * TWB];      // 2 KB
    __shared__ unsigned int flgw[NH * 2];   // 4 KB (4096 flag bytes)

    int t = threadIdx.x;

    // ---- Phase A: exact B-scan, one (h,w) column per thread ----
    int col = blockIdx.x * NTHR + t;
    if (col < PLANE) {
        float d0[NB], dd[NB];
        int nanb = 0;
#pragma unroll
        for (int b = 0; b < NB; ++b) {
            float v = x[(size_t)b * PLANE + col];
            nanb |= (isnan(v) ? (1 << b) : 0);
            d0[b] = (v == 0.0f) ? 0.0f : INF_D;  // NaN != 0 -> foreground
        }
        float cc = INF_D;
#pragma unroll
        for (int b = 0; b < NB; ++b) { cc = fminf(cc + 1.0f, d0[b]); dd[b] = cc; }
        cc = INF_D;
#pragma unroll
        for (int b = NB - 1; b >= 0; --b) { cc = fminf(cc + 1.0f, d0[b]); dd[b] = fminf(dd[b], cc); }
#pragma unroll
        for (int b = 0; b < NB; ++b) {
            int di = (dd[b] >= 1.0e8f) ? 31 : (int)dd[b];  // exact small int
            code[(size_t)b * PLANE + col] =
                (unsigned char)(di | (((nanb >> b) & 1) << 7));
        }
    }
    grid_barrier(&bar[0], &bar[32]);

    // ---- Phase B: min-plus along H (one b, 8-wide w tile, all 512 i) ----
    {
        int b = blockIdx.x & 15;
        int w0 = (blockIdx.x >> 4) * TWB;
        const unsigned char* gb8 = code + (size_t)b * PLANE + w0;
        for (int m = t; m < 1024; m += NTHR) {
            int k = m >> 1;
            int bo = (m & 1) * 4;
            unsigned int u = *reinterpret_cast<const unsigned int*>(gb8 + (size_t)k * NW + bo);
            int kk = k * k;
#pragma unroll
            for (int e = 0; e < 4; ++e) {
                int c = (u >> (8 * e)) & 0xFF;
                int dl = c & 31;
                hs[(bo + e) * HROW + k] = (dl == 31) ? INF2 : (float)(dl * dl + kk);
            }
            flgw[m] = (u >> 7) & 0x01010101u;  // packed flags [k][w]
        }
        __syncthreads();
        {
            int s = t >> 3, w = t & 7;
            const float* hp = &hs[w * HROW + s * 8];
            float4 A = *reinterpret_cast<const float4*>(hp);
            float4 B = *reinterpret_cast<const float4*>(hp + 4);
            int k0 = s * 8;
            float m0 = fminf(fminf(A.x - (float)(k0 * k0), A.y - (float)((k0 + 1) * (k0 + 1))),
                             A.z - (float)((k0 + 2) * (k0 + 2)));
            float m1 = fminf(fminf(A.w - (float)((k0 + 3) * (k0 + 3)), B.x - (float)((k0 + 4) * (k0 + 4))),
                             B.y - (float)((k0 + 5) * (k0 + 5)));
            float m2 = fminf(B.z - (float)((k0 + 6) * (k0 + 6)), B.w - (float)((k0 + 7) * (k0 + 7)));
            smin[t] = fminf(fminf(m0, m1), m2);  // t == s*8+w
        }
        __syncthreads();

        int w = t & 7, q = t >> 3;
        int i0 = q * 8;
        float best[8], neg2i[8], ifl[8];
#pragma unroll
        for (int j = 0; j < 8; ++j) {
            best[j] = BIG;
            ifl[j] = (float)(i0 + j);
            neg2i[j] = (float)(-2 * (i0 + j));
        }
        eval_minplus(&hs[w * HROW], &smin[w], q, best, neg2i, ifl);

        const unsigned char* flgb = reinterpret_cast<const unsigned char*>(flgw);
        float wgf = (float)(w0 + w);
        float* ob = out + (size_t)b * PLANE + w0 + w;
#pragma unroll
        for (int j = 0; j < 8; ++j) {
            float v = fmaf(ifl[j], ifl[j], best[j]);   // exact d^2 after B+H
            float v2 = fmaf(wgf, wgf, v);              // fold W-pass +k^2
            unsigned int bits = __float_as_uint(v2) |
                                ((unsigned int)flgb[(i0 + j) * TWB + w] << 31);
            ob[(size_t)(i0 + j) * NW] = __uint_as_float(bits);
        }
    }
    grid_barrier(&bar[64], &bar[96]);

    // ---- Phase C: min-plus along W, in-place on out, sqrt + NaN mask ----
    {
        int line0 = blockIdx.x * TWB;
        float* gb = out + (size_t)line0 * NW;
        for (int m = t; m < 1024; m += NTHR) {
            float4 v = *reinterpret_cast<const float4*>(gb + (size_t)m * 4);
            int line = m >> 7;
            int k = (m * 4) & 511;
            unsigned int u0 = __float_as_uint(v.x), u1 = __float_as_uint(v.y);
            unsigned int u2 = __float_as_uint(v.z), u3 = __float_as_uint(v.w);
            flgw[m] = (u0 >> 31) | ((u1 >> 31) << 8) |
                      ((u2 >> 31) << 16) | ((u3 >> 31) << 24);
            float4 o;
            o.x = __uint_as_float(u0 & 0x7fffffffu);
            o.y = __uint_as_float(u1 & 0x7fffffffu);
            o.z = __uint_as_float(u2 & 0x7fffffffu);
            o.w = __uint_as_float(u3 & 0x7fffffffu);
            *reinterpret_cast<float4*>(&hs[line * HROW + k]) = o;
        }
        __syncthreads();
        {
            int s = t >> 3, line = t & 7;
            const float* hp = &hs[line * HROW + s * 8];
            float4 A = *reinterpret_cast<const float4*>(hp);
            float4 B = *reinterpret_cast<const float4*>(hp + 4);
            int k0 = s * 8;
            float m0 = fminf(fminf(A.x - (float)(k0 * k0), A.y - (float)((k0 + 1) * (k0 + 1))),
                             A.z - (float)((k0 + 2) * (k0 + 2)));
            float m1 = fminf(fminf(A.w - (float)((k0 + 3) * (k0 + 3)), B.x - (float)((k0 + 4) * (k0 + 4))),
                             B.y - (float)((k0 + 5) * (k0 + 5)));
            float m2 = fminf(B.z - (float)((k0 + 6) * (k0 + 6)), B.w - (float)((k0 + 7) * (k0 + 7)));
            smin[t] = fminf(fminf(m0, m1), m2);
        }
        __syncthreads();

        int line = t & 7, q = t >> 3;
        int i0 = q * 8;
        float best[8], neg2i[8], ifl[8];
#pragma unroll
        for (int j = 0; j < 8; ++j) {
            best[j] = BIG;
            ifl[j] = (float)(i0 + j);
            neg2i[j] = (float)(-2 * (i0 + j));
        }
        eval_minplus(&hs[line * HROW], &smin[line], q, best, neg2i, ifl);

        unsigned int f0 = flgw[(line * NW + i0) >> 2];
        unsigned int f1 = flgw[((line * NW + i0) >> 2) + 1];
        float v[8];
#pragma unroll
        for (int j = 0; j < 8; ++j) {
            float m = fmaf(ifl[j], ifl[j], best[j]);  // exact final d^2
            float sq = sqrtf(m);
            unsigned int fb = (j < 4) ? ((f0 >> (8 * j)) & 1u)
                                      : ((f1 >> (8 * (j - 4))) & 1u);
            v[j] = fb ? __builtin_nanf("") : sq;
        }
        float* op = gb + (size_t)line * NW + i0;
        float4 oa, ob4;
        oa.x = v[0]; oa.y = v[1]; oa.z = v[2]; oa.w = v[3];
        ob4.x = v[4]; ob4.y = v[5]; ob4.z = v[6]; ob4.w = v[7];
        *reinterpret_cast<float4*>(op) = oa;
        *reinterpret_cast<float4*>(op + 4) = ob4;
    }
}

extern "C" void kernel_launch(void* const* d_in, const int* in_sizes, int n_in,
                              void* d_out, int out_size, void* d_ws, size_t ws_size,
                              hipStream_t stream) {
    (void)in_sizes; (void)n_in; (void)out_size; (void)ws_size;
    const float* x = (const float*)d_in[0];
    float* out = (float*)d_out;
    unsigned char* code = (unsigned char*)d_ws;                       // 4.2 MB
    unsigned int* bar = (unsigned int*)((char*)d_ws + (8u << 20));    // +8 MB

    // zero barrier state every call (replay-safe, graph-capturable)
    hipMemsetAsync(bar, 0, 512, stream);
    k_fused<<<dim3(NBLK), dim3(NTHR), 0, stream>>>(x, out, code, bar);
}

// Round 8
// 139.965 us; speedup vs baseline: 1.8954x; 1.8954x over previous
//
#include <hip/hip_runtime.h>
#include <math.h>
#include <stdint.h>

#define NB 16
#define NH 512
#define NW 512
#define PLANE (NH * NW)
#define INF_D 1.0e9f
#define INF2 1.0e18f   // == fl(1e9f*1e9f), matches reference d*d rounding
#define BIG 3.0e38f
#define NSEG 64        // 512 / 8
#define TWB 8          // tile width (cols per block-job)
#define HROW 516       // LDS row stride (floats)
#define NBLK 512
#define NTHR 512

// ---------------------------------------------------------------------------
// Device-scope grid barrier. Co-residency proof: launch_bounds(512,4) caps
// VGPR at 128 -> max 16 waves/CU -> exactly 2 blocks/CU x 256 CUs = 512
// blocks all resident (3 blocks = 24 waves impossible at 128 VGPR; LDS
// 2 x 22.6 KB << 160 KB). R7 lesson: (512,8) forced VGPR=32 -> spill storm.
// ---------------------------------------------------------------------------
__device__ __forceinline__ void grid_barrier(unsigned int* ctr,
                                             unsigned int* flag) {
    __syncthreads();
    if (threadIdx.x == 0) {
        __threadfence();  // release
        unsigned int prev = __hip_atomic_fetch_add(ctr, 1u, __ATOMIC_ACQ_REL,
                                                   __HIP_MEMORY_SCOPE_AGENT);
        if (prev == NBLK - 1) {
            __hip_atomic_store(flag, 1u, __ATOMIC_RELEASE,
                               __HIP_MEMORY_SCOPE_AGENT);
        } else {
            while (__hip_atomic_load(flag, __ATOMIC_ACQUIRE,
                                     __HIP_MEMORY_SCOPE_AGENT) == 0u) {
                __builtin_amdgcn_s_sleep(2);
            }
        }
        __threadfence();  // acquire
    }
    __syncthreads();
}

// ---------------------------------------------------------------------------
// Ring-pruned exact min-plus over one LDS row (h = g + k^2, stride HROW).
// best[j] = min_k(h[k] - 2*i_j*k); true value = i_j^2 + best[j] (exact ints
// < 2^24 on finite path -> bit-exact; INF2 absorbs k^2 shifts).
// ---------------------------------------------------------------------------
__device__ __forceinline__ void eval_minplus(const float* __restrict__ hrow,
                                             const float* __restrict__ sminw,
                                             int q, float* best,
                                             const float* neg2i,
                                             const float* ifl) {
    float bmax = BIG;
    for (int step = 0; step < 2 * NSEG - 1; ++step) {
        int r = (step + 1) >> 1;
        float gapf = (float)(8 * (r - 1) + 1);
        float gap2 = gapf * gapf;
        if ((step & 1) && gap2 >= bmax) break;
        int s = (step & 1) ? (q - r) : (q + r);
        if (s < 0 || s >= NSEG) continue;
        if (step && (gap2 + sminw[s * TWB] >= bmax)) continue;
        const float* hp = hrow + s * 8;
        float4 A = *reinterpret_cast<const float4*>(hp);
        float4 B = *reinterpret_cast<const float4*>(hp + 4);
        float s8f = (float)(s * 8);
#pragma unroll
        for (int j = 0; j < 8; ++j) {
            float n2 = neg2i[j];
            float c0 = fmaf(n2, s8f, A.x);
            float c1 = fmaf(n2, s8f + 1.0f, A.y);
            float c2 = fmaf(n2, s8f + 2.0f, A.z);
            float c3 = fmaf(n2, s8f + 3.0f, A.w);
            float c4 = fmaf(n2, s8f + 4.0f, B.x);
            float c5 = fmaf(n2, s8f + 5.0f, B.y);
            float c6 = fmaf(n2, s8f + 6.0f, B.z);
            float c7 = fmaf(n2, s8f + 7.0f, B.w);
            float bb = fminf(fminf(best[j], c0), c1);
            bb = fminf(fminf(bb, c2), c3);
            bb = fminf(fminf(bb, c4), c5);
            bb = fminf(fminf(bb, c6), c7);
            best[j] = bb;
        }
        float t0 = fmaf(ifl[0], ifl[0], best[0]);
        float t1 = fmaf(ifl[1], ifl[1], best[1]);
        float t2 = fmaf(ifl[2], ifl[2], best[2]);
        float t3 = fmaf(ifl[3], ifl[3], best[3]);
        float t4 = fmaf(ifl[4], ifl[4], best[4]);
        float t5 = fmaf(ifl[5], ifl[5], best[5]);
        float t6 = fmaf(ifl[6], ifl[6], best[6]);
        float t7 = fmaf(ifl[7], ifl[7], best[7]);
        float m = fmaxf(fmaxf(t0, t1), t2);
        m = fmaxf(fmaxf(m, t3), t4);
        m = fmaxf(fmaxf(m, t5), t6);
        bmax = fmaxf(m, t7);
    }
}

// ---------------------------------------------------------------------------
// Fused persistent kernel: A (B-scan -> u8 codes), barrier, B (H min-plus
// x2 jobs, +w^2 folded, NaN flag in sign bit), barrier, C (W min-plus
// x2 jobs in-place, sqrt + NaN). 512 blocks x 512 threads.
// ---------------------------------------------------------------------------
__global__ __launch_bounds__(NTHR, 4) void k_fused(const float* __restrict__ x,
                                                   float* __restrict__ out,
                                                   unsigned char* __restrict__ code,
                                                   unsigned int* __restrict__ bar) {
    __shared__ float hs[TWB * HROW];        // 16.1 KB
    __shared__ float smin[NSEG * TWB];      // 2 KB
    __shared__ unsigned int flgw[NH * 2];   // 4 KB

    int t = threadIdx.x;

    // ---- Phase A: exact B-scan, one (h,w) column per thread ----
    {
        int col = blockIdx.x * NTHR + t;    // 512*512 == PLANE exactly
        float d0[NB], dd[NB];
        int nanb = 0;
#pragma unroll
        for (int b = 0; b < NB; ++b) {
            float v = x[(size_t)b * PLANE + col];
            nanb |= (isnan(v) ? (1 << b) : 0);
            d0[b] = (v == 0.0f) ? 0.0f : INF_D;  // NaN != 0 -> foreground
        }
        float cc = INF_D;
#pragma unroll
        for (int b = 0; b < NB; ++b) { cc = fminf(cc + 1.0f, d0[b]); dd[b] = cc; }
        cc = INF_D;
#pragma unroll
        for (int b = NB - 1; b >= 0; --b) { cc = fminf(cc + 1.0f, d0[b]); dd[b] = fminf(dd[b], cc); }
#pragma unroll
        for (int b = 0; b < NB; ++b) {
            int di = (dd[b] >= 1.0e8f) ? 31 : (int)dd[b];  // exact small int
            code[(size_t)b * PLANE + col] =
                (unsigned char)(di | (((nanb >> b) & 1) << 7));
        }
    }
    grid_barrier(&bar[0], &bar[32]);

    // ---- Phase B: min-plus along H; 2 jobs of (b, 8-wide w tile) ----
    for (int job = blockIdx.x; job < NB * (NW / TWB); job += NBLK) {
        __syncthreads();  // LDS reuse guard (prev job's eval reads done)
        int b = job & 15;
        int w0 = (job >> 4) * TWB;
        const unsigned char* gb8 = code + (size_t)b * PLANE + w0;
        for (int m = t; m < 1024; m += NTHR) {
            int k = m >> 1;
            int bo = (m & 1) * 4;
            unsigned int u = *reinterpret_cast<const unsigned int*>(gb8 + (size_t)k * NW + bo);
            int kk = k * k;
#pragma unroll
            for (int e = 0; e < 4; ++e) {
                int c = (u >> (8 * e)) & 0xFF;
                int dl = c & 31;
                hs[(bo + e) * HROW + k] = (dl == 31) ? INF2 : (float)(dl * dl + kk);
            }
            flgw[m] = (u >> 7) & 0x01010101u;  // packed flags
        }
        __syncthreads();
        {
            int s = t >> 3, w = t & 7;
            const float* hp = &hs[w * HROW + s * 8];
            float4 A = *reinterpret_cast<const float4*>(hp);
            float4 B = *reinterpret_cast<const float4*>(hp + 4);
            int k0 = s * 8;
            float m0 = fminf(fminf(A.x - (float)(k0 * k0), A.y - (float)((k0 + 1) * (k0 + 1))),
                             A.z - (float)((k0 + 2) * (k0 + 2)));
            float m1 = fminf(fminf(A.w - (float)((k0 + 3) * (k0 + 3)), B.x - (float)((k0 + 4) * (k0 + 4))),
                             B.y - (float)((k0 + 5) * (k0 + 5)));
            float m2 = fminf(B.z - (float)((k0 + 6) * (k0 + 6)), B.w - (float)((k0 + 7) * (k0 + 7)));
            smin[t] = fminf(fminf(m0, m1), m2);  // t == s*8+w
        }
        __syncthreads();

        int w = t & 7, q = t >> 3;
        int i0 = q * 8;
        float best[8], neg2i[8], ifl[8];
#pragma unroll
        for (int j = 0; j < 8; ++j) {
            best[j] = BIG;
            ifl[j] = (float)(i0 + j);
            neg2i[j] = (float)(-2 * (i0 + j));
        }
        eval_minplus(&hs[w * HROW], &smin[w], q, best, neg2i, ifl);

        const unsigned char* flgb = reinterpret_cast<const unsigned char*>(flgw);
        float wgf = (float)(w0 + w);
        float* ob = out + (size_t)b * PLANE + w0 + w;
#pragma unroll
        for (int j = 0; j < 8; ++j) {
            float v = fmaf(ifl[j], ifl[j], best[j]);   // exact d^2 after B+H
            float v2 = fmaf(wgf, wgf, v);              // fold W-pass +k^2
            unsigned int bits = __float_as_uint(v2) |
                                ((unsigned int)flgb[(i0 + j) * TWB + w] << 31);
            ob[(size_t)(i0 + j) * NW] = __uint_as_float(bits);
        }
    }
    grid_barrier(&bar[64], &bar[96]);

    // ---- Phase C: min-plus along W; 2 jobs of 8 lines, in-place ----
    for (int job = blockIdx.x; job < (NB * NH) / TWB; job += NBLK) {
        __syncthreads();  // LDS reuse guard
        int line0 = job * TWB;
        float* gb = out + (size_t)line0 * NW;
        for (int m = t; m < 1024; m += NTHR) {
            float4 v = *reinterpret_cast<const float4*>(gb + (size_t)m * 4);
            int line = m >> 7;
            int k = (m * 4) & 511;
            unsigned int u0 = __float_as_uint(v.x), u1 = __float_as_uint(v.y);
            unsigned int u2 = __float_as_uint(v.z), u3 = __float_as_uint(v.w);
            flgw[m] = (u0 >> 31) | ((u1 >> 31) << 8) |
                      ((u2 >> 31) << 16) | ((u3 >> 31) << 24);
            float4 o;
            o.x = __uint_as_float(u0 & 0x7fffffffu);
            o.y = __uint_as_float(u1 & 0x7fffffffu);
            o.z = __uint_as_float(u2 & 0x7fffffffu);
            o.w = __uint_as_float(u3 & 0x7fffffffu);
            *reinterpret_cast<float4*>(&hs[line * HROW + k]) = o;
        }
        __syncthreads();
        {
            int s = t >> 3, line = t & 7;
            const float* hp = &hs[line * HROW + s * 8];
            float4 A = *reinterpret_cast<const float4*>(hp);
            float4 B = *reinterpret_cast<const float4*>(hp + 4);
            int k0 = s * 8;
            float m0 = fminf(fminf(A.x - (float)(k0 * k0), A.y - (float)((k0 + 1) * (k0 + 1))),
                             A.z - (float)((k0 + 2) * (k0 + 2)));
            float m1 = fminf(fminf(A.w - (float)((k0 + 3) * (k0 + 3)), B.x - (float)((k0 + 4) * (k0 + 4))),
                             B.y - (float)((k0 + 5) * (k0 + 5)));
            float m2 = fminf(B.z - (float)((k0 + 6) * (k0 + 6)), B.w - (float)((k0 + 7) * (k0 + 7)));
            smin[t] = fminf(fminf(m0, m1), m2);
        }
        __syncthreads();

        int line = t & 7, q = t >> 3;
        int i0 = q * 8;
        float best[8], neg2i[8], ifl[8];
#pragma unroll
        for (int j = 0; j < 8; ++j) {
            best[j] = BIG;
            ifl[j] = (float)(i0 + j);
            neg2i[j] = (float)(-2 * (i0 + j));
        }
        eval_minplus(&hs[line * HROW], &smin[line], q, best, neg2i, ifl);

        unsigned int f0 = flgw[(line * NW + i0) >> 2];
        unsigned int f1 = flgw[((line * NW + i0) >> 2) + 1];
        float v[8];
#pragma unroll
        for (int j = 0; j < 8; ++j) {
            float m = fmaf(ifl[j], ifl[j], best[j]);  // exact final d^2
            float sq = sqrtf(m);
            unsigned int fb = (j < 4) ? ((f0 >> (8 * j)) & 1u)
                                      : ((f1 >> (8 * (j - 4))) & 1u);
            v[j] = fb ? __builtin_nanf("") : sq;
        }
        float* op = gb + (size_t)line * NW + i0;
        float4 oa, ob4;
        oa.x = v[0]; oa.y = v[1]; oa.z = v[2]; oa.w = v[3];
        ob4.x = v[4]; ob4.y = v[5]; ob4.z = v[6]; ob4.w = v[7];
        *reinterpret_cast<float4*>(op) = oa;
        *reinterpret_cast<float4*>(op + 4) = ob4;
    }
}

extern "C" void kernel_launch(void* const* d_in, const int* in_sizes, int n_in,
                              void* d_out, int out_size, void* d_ws, size_t ws_size,
                              hipStream_t stream) {
    (void)in_sizes; (void)n_in; (void)out_size; (void)ws_size;
    const float* x = (const float*)d_in[0];
    float* out = (float*)d_out;
    unsigned char* code = (unsigned char*)d_ws;                       // 4.2 MB
    unsigned int* bar = (unsigned int*)((char*)d_ws + (8u << 20));    // +8 MB

    hipMemsetAsync(bar, 0, 512, stream);  // replay-safe barrier reset
    k_fused<<<dim3(NBLK), dim3(NTHR), 0, stream>>>(x, out, code, bar);
}

// Round 9
// 90.561 us; speedup vs baseline: 2.9294x; 1.5455x over previous
//
#include <hip/hip_runtime.h>
#include <math.h>
#include <stdint.h>

#define NB 16
#define NH 512
#define NW 512
#define PLANE (NH * NW)
#define INF_D 1.0e9f
#define INF2 1.0e18f   // == fl(1e9f*1e9f), matches reference d*d rounding
#define BIG 3.0e38f
#define NSEG 64        // 512 / 8
#define TWB 8          // tile width (cols per block-job)
#define HROW 516       // LDS row stride (floats)
#define NBLK 512
#define NTHR 512

// ---------------------------------------------------------------------------
// Device-scope grid barrier. Co-residency: 512 blocks x 8 waves = 2 blocks/CU
// on 256 CUs (16 waves <= 32; LDS 2x22.6KB << 160KB).
// R8 lesson: ACQUIRE atomic loads in the spin loop emit L2 cache-maintenance
// PER POLL -> TCC serialization + evicting working blocks (VALUBusy 11%).
// Fix: RELAXED polls (read-through, no maintenance) + ONE threadfence after.
// ---------------------------------------------------------------------------
__device__ __forceinline__ void grid_barrier(unsigned int* ctr,
                                             unsigned int* flag) {
    __syncthreads();
    if (threadIdx.x == 0) {
        __threadfence();  // release: one L2 writeback for this block's stores
        unsigned int prev = __hip_atomic_fetch_add(ctr, 1u, __ATOMIC_RELAXED,
                                                   __HIP_MEMORY_SCOPE_AGENT);
        if (prev == NBLK - 1) {
            __hip_atomic_store(flag, 1u, __ATOMIC_RELAXED,
                               __HIP_MEMORY_SCOPE_AGENT);
        } else {
            while (__hip_atomic_load(flag, __ATOMIC_RELAXED,
                                     __HIP_MEMORY_SCOPE_AGENT) == 0u) {
                __builtin_amdgcn_s_sleep(8);
            }
        }
        __threadfence();  // acquire: ONE invalidate before reading remote data
    }
    __syncthreads();
}

// ---------------------------------------------------------------------------
// Ring-pruned exact min-plus over one LDS row (h = g + k^2, stride HROW).
// best[j] = min_k(h[k] - 2*i_j*k); true value = i_j^2 + best[j] (exact ints
// < 2^24 on finite path -> bit-exact; INF2 absorbs k^2 shifts).
// ---------------------------------------------------------------------------
__device__ __forceinline__ void eval_minplus(const float* __restrict__ hrow,
                                             const float* __restrict__ sminw,
                                             int q, float* best,
                                             const float* neg2i,
                                             const float* ifl) {
    float bmax = BIG;
    for (int step = 0; step < 2 * NSEG - 1; ++step) {
        int r = (step + 1) >> 1;
        float gapf = (float)(8 * (r - 1) + 1);
        float gap2 = gapf * gapf;
        if ((step & 1) && gap2 >= bmax) break;
        int s = (step & 1) ? (q - r) : (q + r);
        if (s < 0 || s >= NSEG) continue;
        if (step && (gap2 + sminw[s * TWB] >= bmax)) continue;
        const float* hp = hrow + s * 8;
        float4 A = *reinterpret_cast<const float4*>(hp);
        float4 B = *reinterpret_cast<const float4*>(hp + 4);
        float s8f = (float)(s * 8);
#pragma unroll
        for (int j = 0; j < 8; ++j) {
            float n2 = neg2i[j];
            float c0 = fmaf(n2, s8f, A.x);
            float c1 = fmaf(n2, s8f + 1.0f, A.y);
            float c2 = fmaf(n2, s8f + 2.0f, A.z);
            float c3 = fmaf(n2, s8f + 3.0f, A.w);
            float c4 = fmaf(n2, s8f + 4.0f, B.x);
            float c5 = fmaf(n2, s8f + 5.0f, B.y);
            float c6 = fmaf(n2, s8f + 6.0f, B.z);
            float c7 = fmaf(n2, s8f + 7.0f, B.w);
            float bb = fminf(fminf(best[j], c0), c1);
            bb = fminf(fminf(bb, c2), c3);
            bb = fminf(fminf(bb, c4), c5);
            bb = fminf(fminf(bb, c6), c7);
            best[j] = bb;
        }
        float t0 = fmaf(ifl[0], ifl[0], best[0]);
        float t1 = fmaf(ifl[1], ifl[1], best[1]);
        float t2 = fmaf(ifl[2], ifl[2], best[2]);
        float t3 = fmaf(ifl[3], ifl[3], best[3]);
        float t4 = fmaf(ifl[4], ifl[4], best[4]);
        float t5 = fmaf(ifl[5], ifl[5], best[5]);
        float t6 = fmaf(ifl[6], ifl[6], best[6]);
        float t7 = fmaf(ifl[7], ifl[7], best[7]);
        float m = fmaxf(fmaxf(t0, t1), t2);
        m = fmaxf(fmaxf(m, t3), t4);
        m = fmaxf(fmaxf(m, t5), t6);
        bmax = fmaxf(m, t7);
    }
}

// ---------------------------------------------------------------------------
// Fused persistent kernel: A (B-scan -> u8 codes), barrier, B (H min-plus
// x2 jobs, +w^2 folded, NaN flag in sign bit), barrier, C (W min-plus
// x2 jobs in-place, sqrt + NaN). 512 blocks x 512 threads.
// ---------------------------------------------------------------------------
__global__ __launch_bounds__(NTHR, 4) void k_fused(const float* __restrict__ x,
                                                   float* __restrict__ out,
                                                   unsigned char* __restrict__ code,
                                                   unsigned int* __restrict__ bar) {
    __shared__ float hs[TWB * HROW];        // 16.1 KB
    __shared__ float smin[NSEG * TWB];      // 2 KB
    __shared__ unsigned int flgw[NH * 2];   // 4 KB

    int t = threadIdx.x;

    // ---- Phase A: exact B-scan, one (h,w) column per thread ----
    {
        int col = blockIdx.x * NTHR + t;    // 512*512 == PLANE exactly
        float d0[NB], dd[NB];
        int nanb = 0;
#pragma unroll
        for (int b = 0; b < NB; ++b) {
            float v = x[(size_t)b * PLANE + col];
            nanb |= (isnan(v) ? (1 << b) : 0);
            d0[b] = (v == 0.0f) ? 0.0f : INF_D;  // NaN != 0 -> foreground
        }
        float cc = INF_D;
#pragma unroll
        for (int b = 0; b < NB; ++b) { cc = fminf(cc + 1.0f, d0[b]); dd[b] = cc; }
        cc = INF_D;
#pragma unroll
        for (int b = NB - 1; b >= 0; --b) { cc = fminf(cc + 1.0f, d0[b]); dd[b] = fminf(dd[b], cc); }
#pragma unroll
        for (int b = 0; b < NB; ++b) {
            int di = (dd[b] >= 1.0e8f) ? 31 : (int)dd[b];  // exact small int
            code[(size_t)b * PLANE + col] =
                (unsigned char)(di | (((nanb >> b) & 1) << 7));
        }
    }
    grid_barrier(&bar[0], &bar[32]);

    // ---- Phase B: min-plus along H; 2 jobs of (b, 8-wide w tile) ----
    for (int job = blockIdx.x; job < NB * (NW / TWB); job += NBLK) {
        __syncthreads();  // LDS reuse guard (prev job's eval reads done)
        int b = job & 15;
        int w0 = (job >> 4) * TWB;
        const unsigned char* gb8 = code + (size_t)b * PLANE + w0;
        for (int m = t; m < 1024; m += NTHR) {
            int k = m >> 1;
            int bo = (m & 1) * 4;
            unsigned int u = *reinterpret_cast<const unsigned int*>(gb8 + (size_t)k * NW + bo);
            int kk = k * k;
#pragma unroll
            for (int e = 0; e < 4; ++e) {
                int c = (u >> (8 * e)) & 0xFF;
                int dl = c & 31;
                hs[(bo + e) * HROW + k] = (dl == 31) ? INF2 : (float)(dl * dl + kk);
            }
            flgw[m] = (u >> 7) & 0x01010101u;  // packed flags
        }
        __syncthreads();
        {
            int s = t >> 3, w = t & 7;
            const float* hp = &hs[w * HROW + s * 8];
            float4 A = *reinterpret_cast<const float4*>(hp);
            float4 B = *reinterpret_cast<const float4*>(hp + 4);
            int k0 = s * 8;
            float m0 = fminf(fminf(A.x - (float)(k0 * k0), A.y - (float)((k0 + 1) * (k0 + 1))),
                             A.z - (float)((k0 + 2) * (k0 + 2)));
            float m1 = fminf(fminf(A.w - (float)((k0 + 3) * (k0 + 3)), B.x - (float)((k0 + 4) * (k0 + 4))),
                             B.y - (float)((k0 + 5) * (k0 + 5)));
            float m2 = fminf(B.z - (float)((k0 + 6) * (k0 + 6)), B.w - (float)((k0 + 7) * (k0 + 7)));
            smin[t] = fminf(fminf(m0, m1), m2);  // t == s*8+w
        }
        __syncthreads();

        int w = t & 7, q = t >> 3;
        int i0 = q * 8;
        float best[8], neg2i[8], ifl[8];
#pragma unroll
        for (int j = 0; j < 8; ++j) {
            best[j] = BIG;
            ifl[j] = (float)(i0 + j);
            neg2i[j] = (float)(-2 * (i0 + j));
        }
        eval_minplus(&hs[w * HROW], &smin[w], q, best, neg2i, ifl);

        const unsigned char* flgb = reinterpret_cast<const unsigned char*>(flgw);
        float wgf = (float)(w0 + w);
        float* ob = out + (size_t)b * PLANE + w0 + w;
#pragma unroll
        for (int j = 0; j < 8; ++j) {
            float v = fmaf(ifl[j], ifl[j], best[j]);   // exact d^2 after B+H
            float v2 = fmaf(wgf, wgf, v);              // fold W-pass +k^2
            unsigned int bits = __float_as_uint(v2) |
                                ((unsigned int)flgb[(i0 + j) * TWB + w] << 31);
            ob[(size_t)(i0 + j) * NW] = __uint_as_float(bits);
        }
    }
    grid_barrier(&bar[64], &bar[96]);

    // ---- Phase C: min-plus along W; 2 jobs of 8 lines, in-place ----
    for (int job = blockIdx.x; job < (NB * NH) / TWB; job += NBLK) {
        __syncthreads();  // LDS reuse guard
        int line0 = job * TWB;
        float* gb = out + (size_t)line0 * NW;
        for (int m = t; m < 1024; m += NTHR) {
            float4 v = *reinterpret_cast<const float4*>(gb + (size_t)m * 4);
            int line = m >> 7;
            int k = (m * 4) & 511;
            unsigned int u0 = __float_as_uint(v.x), u1 = __float_as_uint(v.y);
            unsigned int u2 = __float_as_uint(v.z), u3 = __float_as_uint(v.w);
            flgw[m] = (u0 >> 31) | ((u1 >> 31) << 8) |
                      ((u2 >> 31) << 16) | ((u3 >> 31) << 24);
            float4 o;
            o.x = __uint_as_float(u0 & 0x7fffffffu);
            o.y = __uint_as_float(u1 & 0x7fffffffu);
            o.z = __uint_as_float(u2 & 0x7fffffffu);
            o.w = __uint_as_float(u3 & 0x7fffffffu);
            *reinterpret_cast<float4*>(&hs[line * HROW + k]) = o;
        }
        __syncthreads();
        {
            int s = t >> 3, line = t & 7;
            const float* hp = &hs[line * HROW + s * 8];
            float4 A = *reinterpret_cast<const float4*>(hp);
            float4 B = *reinterpret_cast<const float4*>(hp + 4);
            int k0 = s * 8;
            float m0 = fminf(fminf(A.x - (float)(k0 * k0), A.y - (float)((k0 + 1) * (k0 + 1))),
                             A.z - (float)((k0 + 2) * (k0 + 2)));
            float m1 = fminf(fminf(A.w - (float)((k0 + 3) * (k0 + 3)), B.x - (float)((k0 + 4) * (k0 + 4))),
                             B.y - (float)((k0 + 5) * (k0 + 5)));
            float m2 = fminf(B.z - (float)((k0 + 6) * (k0 + 6)), B.w - (float)((k0 + 7) * (k0 + 7)));
            smin[t] = fminf(fminf(m0, m1), m2);
        }
        __syncthreads();

        int line = t & 7, q = t >> 3;
        int i0 = q * 8;
        float best[8], neg2i[8], ifl[8];
#pragma unroll
        for (int j = 0; j < 8; ++j) {
            best[j] = BIG;
            ifl[j] = (float)(i0 + j);
            neg2i[j] = (float)(-2 * (i0 + j));
        }
        eval_minplus(&hs[line * HROW], &smin[line], q, best, neg2i, ifl);

        unsigned int f0 = flgw[(line * NW + i0) >> 2];
        unsigned int f1 = flgw[((line * NW + i0) >> 2) + 1];
        float v[8];
#pragma unroll
        for (int j = 0; j < 8; ++j) {
            float m = fmaf(ifl[j], ifl[j], best[j]);  // exact final d^2
            float sq = sqrtf(m);
            unsigned int fb = (j < 4) ? ((f0 >> (8 * j)) & 1u)
                                      : ((f1 >> (8 * (j - 4))) & 1u);
            v[j] = fb ? __builtin_nanf("") : sq;
        }
        float* op = gb + (size_t)line * NW + i0;
        float4 oa, ob4;
        oa.x = v[0]; oa.y = v[1]; oa.z = v[2]; oa.w = v[3];
        ob4.x = v[4]; ob4.y = v[5]; ob4.z = v[6]; ob4.w = v[7];
        *reinterpret_cast<float4*>(op) = oa;
        *reinterpret_cast<float4*>(op + 4) = ob4;
    }
}

extern "C" void kernel_launch(void* const* d_in, const int* in_sizes, int n_in,
                              void* d_out, int out_size, void* d_ws, size_t ws_size,
                              hipStream_t stream) {
    (void)in_sizes; (void)n_in; (void)out_size; (void)ws_size;
    const float* x = (const float*)d_in[0];
    float* out = (float*)d_out;
    unsigned char* code = (unsigned char*)d_ws;                       // 4.2 MB
    unsigned int* bar = (unsigned int*)((char*)d_ws + (8u << 20));    // +8 MB

    hipMemsetAsync(bar, 0, 512, stream);  // replay-safe barrier reset
    k_fused<<<dim3(NBLK), dim3(NTHR), 0, stream>>>(x, out, code, bar);
}

// Round 10
// 36.891 us; speedup vs baseline: 7.1912x; 2.4548x over previous
//
#include <hip/hip_runtime.h>
#include <math.h>
#include <stdint.h>

#define NB 16
#define NH 512
#define NW 512
#define PLANE (NH * NW)
#define INF_D 1.0e9f
#define INF2 1.0e18f   // == fl(1e9f*1e9f), matches reference d*d rounding
#define BIG 3.0e38f
#define NSEG 64        // 512 / 8
#define TWB 8          // tile width (cols/lines per block)
#define HROW 516       // LDS row stride (floats)

// ---------------------------------------------------------------------------
// Ring-pruned exact min-plus over one LDS row (h = g + k^2, stride HROW).
// best[j] = min_k(h[k] - 2*i_j*k); true value = i_j^2 + best[j] (exact ints
// < 2^24 on finite path -> bit-exact; INF2 absorbs k^2 shifts).
// ---------------------------------------------------------------------------
__device__ __forceinline__ void eval_minplus(const float* __restrict__ hrow,
                                             const float* __restrict__ sminw,
                                             int q, float* best,
                                             const float* neg2i,
                                             const float* ifl) {
    float bmax = BIG;
    for (int step = 0; step < 2 * NSEG - 1; ++step) {
        int r = (step + 1) >> 1;
        float gapf = (float)(8 * (r - 1) + 1);
        float gap2 = gapf * gapf;
        if ((step & 1) && gap2 >= bmax) break;
        int s = (step & 1) ? (q - r) : (q + r);
        if (s < 0 || s >= NSEG) continue;
        if (step && (gap2 + sminw[s * TWB] >= bmax)) continue;
        const float* hp = hrow + s * 8;
        float4 A = *reinterpret_cast<const float4*>(hp);
        float4 B = *reinterpret_cast<const float4*>(hp + 4);
        float s8f = (float)(s * 8);
#pragma unroll
        for (int j = 0; j < 8; ++j) {
            float n2 = neg2i[j];
            float c0 = fmaf(n2, s8f, A.x);
            float c1 = fmaf(n2, s8f + 1.0f, A.y);
            float c2 = fmaf(n2, s8f + 2.0f, A.z);
            float c3 = fmaf(n2, s8f + 3.0f, A.w);
            float c4 = fmaf(n2, s8f + 4.0f, B.x);
            float c5 = fmaf(n2, s8f + 5.0f, B.y);
            float c6 = fmaf(n2, s8f + 6.0f, B.z);
            float c7 = fmaf(n2, s8f + 7.0f, B.w);
            float bb = fminf(fminf(best[j], c0), c1);
            bb = fminf(fminf(bb, c2), c3);
            bb = fminf(fminf(bb, c4), c5);
            bb = fminf(fminf(bb, c6), c7);
            best[j] = bb;
        }
        float t0 = fmaf(ifl[0], ifl[0], best[0]);
        float t1 = fmaf(ifl[1], ifl[1], best[1]);
        float t2 = fmaf(ifl[2], ifl[2], best[2]);
        float t3 = fmaf(ifl[3], ifl[3], best[3]);
        float t4 = fmaf(ifl[4], ifl[4], best[4]);
        float t5 = fmaf(ifl[5], ifl[5], best[5]);
        float t6 = fmaf(ifl[6], ifl[6], best[6]);
        float t7 = fmaf(ifl[7], ifl[7], best[7]);
        float m = fmaxf(fmaxf(t0, t1), t2);
        m = fmaxf(fmaxf(m, t3), t4);
        m = fmaxf(fmaxf(m, t5), t6);
        bmax = fmaxf(m, t7);
    }
}

// ---------------------------------------------------------------------------
// K1: exact B-scan -> u8 codes. 1 col/thread, fully coalesced (256B/instr).
// code = d (0..15 finite, 31 = INF) | (isnan(x) << 7).
// ---------------------------------------------------------------------------
__global__ __launch_bounds__(256, 4) void k_pass_b(const float* __restrict__ x,
                                                   unsigned char* __restrict__ code) {
    int col = blockIdx.x * 256 + threadIdx.x;   // 1024 blocks * 256 == PLANE
    float d0[NB], dd[NB];
    int nanb = 0;
#pragma unroll
    for (int b = 0; b < NB; ++b) {
        float v = x[(size_t)b * PLANE + col];
        nanb |= (isnan(v) ? (1 << b) : 0);
        d0[b] = (v == 0.0f) ? 0.0f : INF_D;     // NaN != 0 -> foreground
    }
    float cc = INF_D;
#pragma unroll
    for (int b = 0; b < NB; ++b) { cc = fminf(cc + 1.0f, d0[b]); dd[b] = cc; }
    cc = INF_D;
#pragma unroll
    for (int b = NB - 1; b >= 0; --b) { cc = fminf(cc + 1.0f, d0[b]); dd[b] = fminf(dd[b], cc); }
#pragma unroll
    for (int b = 0; b < NB; ++b) {
        int di = (dd[b] >= 1.0e8f) ? 31 : (int)dd[b];  // exact small int
        code[(size_t)b * PLANE + col] =
            (unsigned char)(di | (((nanb >> b) & 1) << 7));
    }
}

// ---------------------------------------------------------------------------
// K2: min-plus along H. 512 thr, one (b, 8-wide w tile). Grid (64, 16) =
// 1024 blocks -> 4 blocks/CU (VGPR 48 <= 64, LDS 22.6KB) = 32 waves/CU.
// Writes fl(fl(i^2+best) + w^2) with NaN flag in sign bit.
// ---------------------------------------------------------------------------
__global__ __launch_bounds__(512, 4) void k_pass_h(const unsigned char* __restrict__ code,
                                                   float* __restrict__ out) {
    __shared__ float hs[TWB * HROW];        // 16.1 KB
    __shared__ float smin[NSEG * TWB];      // 2 KB
    __shared__ unsigned int flgw[NH * 2];   // 4 KB
    int t = threadIdx.x;
    int b = blockIdx.y;
    int w0 = blockIdx.x * TWB;
    const unsigned char* gb8 = code + (size_t)b * PLANE + w0;

    for (int m = t; m < 1024; m += 512) {
        int k = m >> 1;
        int bo = (m & 1) * 4;
        unsigned int u = *reinterpret_cast<const unsigned int*>(gb8 + (size_t)k * NW + bo);
        int kk = k * k;
#pragma unroll
        for (int e = 0; e < 4; ++e) {
            int c = (u >> (8 * e)) & 0xFF;
            int dl = c & 31;
            hs[(bo + e) * HROW + k] = (dl == 31) ? INF2 : (float)(dl * dl + kk);
        }
        flgw[m] = (u >> 7) & 0x01010101u;   // packed flags
    }
    __syncthreads();
    {
        int s = t >> 3, w = t & 7;
        const float* hp = &hs[w * HROW + s * 8];
        float4 A = *reinterpret_cast<const float4*>(hp);
        float4 B = *reinterpret_cast<const float4*>(hp + 4);
        int k0 = s * 8;
        float m0 = fminf(fminf(A.x - (float)(k0 * k0), A.y - (float)((k0 + 1) * (k0 + 1))),
                         A.z - (float)((k0 + 2) * (k0 + 2)));
        float m1 = fminf(fminf(A.w - (float)((k0 + 3) * (k0 + 3)), B.x - (float)((k0 + 4) * (k0 + 4))),
                         B.y - (float)((k0 + 5) * (k0 + 5)));
        float m2 = fminf(B.z - (float)((k0 + 6) * (k0 + 6)), B.w - (float)((k0 + 7) * (k0 + 7)));
        smin[t] = fminf(fminf(m0, m1), m2); // t == s*8+w
    }
    __syncthreads();

    int w = t & 7, q = t >> 3;
    int i0 = q * 8;
    float best[8], neg2i[8], ifl[8];
#pragma unroll
    for (int j = 0; j < 8; ++j) {
        best[j] = BIG;
        ifl[j] = (float)(i0 + j);
        neg2i[j] = (float)(-2 * (i0 + j));
    }
    eval_minplus(&hs[w * HROW], &smin[w], q, best, neg2i, ifl);

    const unsigned char* flgb = reinterpret_cast<const unsigned char*>(flgw);
    float wgf = (float)(w0 + w);
    float* ob = out + (size_t)b * PLANE + w0 + w;
#pragma unroll
    for (int j = 0; j < 8; ++j) {
        float v = fmaf(ifl[j], ifl[j], best[j]);   // exact d^2 after B+H
        float v2 = fmaf(wgf, wgf, v);              // fold W-pass +k^2 (exact)
        unsigned int bits = __float_as_uint(v2) |
                            ((unsigned int)flgb[(i0 + j) * TWB + w] << 31);
        ob[(size_t)(i0 + j) * NW] = __uint_as_float(bits);
    }
}

// ---------------------------------------------------------------------------
// K3: min-plus along W, in-place on out, 8 lines/block, 1024 blocks.
// +k^2 pre-folded by K2; NaN flag in sign bit; sqrt + NaN epilogue.
// ---------------------------------------------------------------------------
__global__ __launch_bounds__(512, 4) void k_pass_w(float* __restrict__ out) {
    __shared__ float hs[TWB * HROW];
    __shared__ float smin[NSEG * TWB];
    __shared__ unsigned int flgw[NH * 2];
    int t = threadIdx.x;
    int line0 = blockIdx.x * TWB;
    float* gb = out + (size_t)line0 * NW;

    for (int m = t; m < 1024; m += 512) {
        float4 v = *reinterpret_cast<const float4*>(gb + (size_t)m * 4);
        int line = m >> 7;
        int k = (m * 4) & 511;
        unsigned int u0 = __float_as_uint(v.x), u1 = __float_as_uint(v.y);
        unsigned int u2 = __float_as_uint(v.z), u3 = __float_as_uint(v.w);
        flgw[m] = (u0 >> 31) | ((u1 >> 31) << 8) |
                  ((u2 >> 31) << 16) | ((u3 >> 31) << 24);
        float4 o;
        o.x = __uint_as_float(u0 & 0x7fffffffu);
        o.y = __uint_as_float(u1 & 0x7fffffffu);
        o.z = __uint_as_float(u2 & 0x7fffffffu);
        o.w = __uint_as_float(u3 & 0x7fffffffu);
        *reinterpret_cast<float4*>(&hs[line * HROW + k]) = o;
    }
    __syncthreads();
    {
        int s = t >> 3, line = t & 7;
        const float* hp = &hs[line * HROW + s * 8];
        float4 A = *reinterpret_cast<const float4*>(hp);
        float4 B = *reinterpret_cast<const float4*>(hp + 4);
        int k0 = s * 8;
        float m0 = fminf(fminf(A.x - (float)(k0 * k0), A.y - (float)((k0 + 1) * (k0 + 1))),
                         A.z - (float)((k0 + 2) * (k0 + 2)));
        float m1 = fminf(fminf(A.w - (float)((k0 + 3) * (k0 + 3)), B.x - (float)((k0 + 4) * (k0 + 4))),
                         B.y - (float)((k0 + 5) * (k0 + 5)));
        float m2 = fminf(B.z - (float)((k0 + 6) * (k0 + 6)), B.w - (float)((k0 + 7) * (k0 + 7)));
        smin[t] = fminf(fminf(m0, m1), m2);
    }
    __syncthreads();

    int line = t & 7, q = t >> 3;
    int i0 = q * 8;
    float best[8], neg2i[8], ifl[8];
#pragma unroll
    for (int j = 0; j < 8; ++j) {
        best[j] = BIG;
        ifl[j] = (float)(i0 + j);
        neg2i[j] = (float)(-2 * (i0 + j));
    }
    eval_minplus(&hs[line * HROW], &smin[line], q, best, neg2i, ifl);

    unsigned int f0 = flgw[(line * NW + i0) >> 2];
    unsigned int f1 = flgw[((line * NW + i0) >> 2) + 1];
    float v[8];
#pragma unroll
    for (int j = 0; j < 8; ++j) {
        float m = fmaf(ifl[j], ifl[j], best[j]);  // exact final d^2
        float sq = sqrtf(m);
        unsigned int fb = (j < 4) ? ((f0 >> (8 * j)) & 1u)
                                  : ((f1 >> (8 * (j - 4))) & 1u);
        v[j] = fb ? __builtin_nanf("") : sq;
    }
    float* op = gb + (size_t)line * NW + i0;
    float4 oa, ob4;
    oa.x = v[0]; oa.y = v[1]; oa.z = v[2]; oa.w = v[3];
    ob4.x = v[4]; ob4.y = v[5]; ob4.z = v[6]; ob4.w = v[7];
    *reinterpret_cast<float4*>(op) = oa;
    *reinterpret_cast<float4*>(op + 4) = ob4;
}

extern "C" void kernel_launch(void* const* d_in, const int* in_sizes, int n_in,
                              void* d_out, int out_size, void* d_ws, size_t ws_size,
                              hipStream_t stream) {
    (void)in_sizes; (void)n_in; (void)out_size; (void)ws_size;
    const float* x = (const float*)d_in[0];
    float* out = (float*)d_out;
    unsigned char* code = (unsigned char*)d_ws;  // 4.2 MB u8 codes

    // K1: x -> u8 codes (d along B + NaN flag)
    k_pass_b<<<dim3(PLANE / 256), 256, 0, stream>>>(x, code);
    // K2: min-plus along H: codes -> out (+w^2 folded, NaN in sign bit)
    k_pass_h<<<dim3(NW / TWB, NB), 512, 0, stream>>>(code, out);
    // K3: min-plus along W, in-place on out, sqrt + NaN mask
    k_pass_w<<<dim3(NB * NH / TWB), 512, 0, stream>>>(out);
}

// Round 11
// 36.587 us; speedup vs baseline: 7.2508x; 1.0083x over previous
//
#include <hip/hip_runtime.h>
#include <math.h>
#include <stdint.h>

#define NB 16
#define NH 512
#define NW 512
#define PLANE (NH * NW)
#define INF_D 1.0e9f
#define INF2 1.0e18f   // == fl(1e9f*1e9f), matches reference d*d rounding
#define BIG 3.0e38f
#define NSEG 64        // 512 / 8
#define TWB 8          // tile width (cols/lines per block)
#define HROW 516       // LDS row stride (floats)

// ---------------------------------------------------------------------------
// One 8-wide segment of the exact min-plus: best[j] = min(best[j],
// h[k] - 2*i_j*k) for k in [ss*8, ss*8+8). Exact ints < 2^24 on the finite
// path -> bit-exact; INF2 absorbs the k^2 shift. min3-pair form.
// ---------------------------------------------------------------------------
__device__ __forceinline__ void eval_seg(const float* __restrict__ hrow,
                                         int ss, float* best,
                                         const float* neg2i) {
    const float* hp = hrow + ss * 8;
    float4 A = *reinterpret_cast<const float4*>(hp);
    float4 B = *reinterpret_cast<const float4*>(hp + 4);
    float s8f = (float)(ss * 8);
#pragma unroll
    for (int j = 0; j < 8; ++j) {
        float n2 = neg2i[j];
        float c0 = fmaf(n2, s8f, A.x);
        float c1 = fmaf(n2, s8f + 1.0f, A.y);
        float c2 = fmaf(n2, s8f + 2.0f, A.z);
        float c3 = fmaf(n2, s8f + 3.0f, A.w);
        float c4 = fmaf(n2, s8f + 4.0f, B.x);
        float c5 = fmaf(n2, s8f + 5.0f, B.y);
        float c6 = fmaf(n2, s8f + 6.0f, B.z);
        float c7 = fmaf(n2, s8f + 7.0f, B.w);
        float bb = fminf(fminf(best[j], c0), c1);
        bb = fminf(fminf(bb, c2), c3);
        bb = fminf(fminf(bb, c4), c5);
        bb = fminf(fminf(bb, c6), c7);
        best[j] = bb;
    }
}

// ---------------------------------------------------------------------------
// Window eval: home+ring1 (static, branch-free), then a sqrt(bmax) window
// evaluated unconditionally. No smin, no serial prune chain. The window is
// conservative (g >= 0 => |i-k| <= sqrt(bmax) required to win) so the
// candidate superset always contains the argmin -> exact min unchanged.
// ---------------------------------------------------------------------------
__device__ __forceinline__ void eval_minplus(const float* __restrict__ hrow,
                                             int q, float* best,
                                             const float* neg2i,
                                             const float* ifl) {
    int s_lo0 = (q > 0) ? q - 1 : 0;
    int s_hi0 = (q < NSEG - 1) ? q + 1 : NSEG - 1;
    for (int ss = s_lo0; ss <= s_hi0; ++ss) eval_seg(hrow, ss, best, neg2i);

    float t0 = fmaf(ifl[0], ifl[0], best[0]);
    float t1 = fmaf(ifl[1], ifl[1], best[1]);
    float t2 = fmaf(ifl[2], ifl[2], best[2]);
    float t3 = fmaf(ifl[3], ifl[3], best[3]);
    float t4 = fmaf(ifl[4], ifl[4], best[4]);
    float t5 = fmaf(ifl[5], ifl[5], best[5]);
    float t6 = fmaf(ifl[6], ifl[6], best[6]);
    float t7 = fmaf(ifl[7], ifl[7], best[7]);
    float m = fmaxf(fmaxf(t0, t1), t2);
    m = fmaxf(fmaxf(m, t3), t4);
    m = fmaxf(fmaxf(m, t5), t6);
    float bmax = fmaxf(m, t7);

    int sw = (int)sqrtf(bmax) + 1;   // conservative (+1 covers 1-ulp sqrt)
    int i0 = q * 8;
    int s_lo = (i0 - sw) >> 3;       // arithmetic shift floors negatives
    int s_hi = (i0 + 7 + sw) >> 3;
    if (s_lo < 0) s_lo = 0;
    if (s_hi > NSEG - 1) s_hi = NSEG - 1;
    for (int ss = s_lo; ss <= s_hi; ++ss) {
        if (ss >= s_lo0 && ss <= s_hi0) continue;  // already done
        eval_seg(hrow, ss, best, neg2i);
    }
}

// ---------------------------------------------------------------------------
// K1: exact B-scan -> u8 codes. 1 col/thread, fully coalesced.
// code = d (0..15 finite, 31 = INF) | (isnan(x) << 7).
// ---------------------------------------------------------------------------
__global__ __launch_bounds__(256, 4) void k_pass_b(const float* __restrict__ x,
                                                   unsigned char* __restrict__ code) {
    int col = blockIdx.x * 256 + threadIdx.x;   // 1024 blocks * 256 == PLANE
    float d0[NB], dd[NB];
    int nanb = 0;
#pragma unroll
    for (int b = 0; b < NB; ++b) {
        float v = x[(size_t)b * PLANE + col];
        nanb |= (isnan(v) ? (1 << b) : 0);
        d0[b] = (v == 0.0f) ? 0.0f : INF_D;     // NaN != 0 -> foreground
    }
    float cc = INF_D;
#pragma unroll
    for (int b = 0; b < NB; ++b) { cc = fminf(cc + 1.0f, d0[b]); dd[b] = cc; }
    cc = INF_D;
#pragma unroll
    for (int b = NB - 1; b >= 0; --b) { cc = fminf(cc + 1.0f, d0[b]); dd[b] = fminf(dd[b], cc); }
#pragma unroll
    for (int b = 0; b < NB; ++b) {
        int di = (dd[b] >= 1.0e8f) ? 31 : (int)dd[b];  // exact small int
        code[(size_t)b * PLANE + col] =
            (unsigned char)(di | (((nanb >> b) & 1) << 7));
    }
}

// ---------------------------------------------------------------------------
// K2: min-plus along H. 512 thr, one (b, 8-wide w tile). Grid (64,16) =
// 1024 blocks -> 4/CU (VGPR<=64, LDS 20.6KB) = 32 waves/CU.
// Writes fl(fl(i^2+best) + w^2) with NaN flag in sign bit.
// ---------------------------------------------------------------------------
__global__ __launch_bounds__(512, 4) void k_pass_h(const unsigned char* __restrict__ code,
                                                   float* __restrict__ out) {
    __shared__ float hs[TWB * HROW];        // 16.1 KB
    __shared__ unsigned int flgw[NH * 2];   // 4 KB
    int t = threadIdx.x;
    int b = blockIdx.y;
    int w0 = blockIdx.x * TWB;
    const unsigned char* gb8 = code + (size_t)b * PLANE + w0;

    for (int m = t; m < 1024; m += 512) {
        int k = m >> 1;
        int bo = (m & 1) * 4;
        unsigned int u = *reinterpret_cast<const unsigned int*>(gb8 + (size_t)k * NW + bo);
        int kk = k * k;
#pragma unroll
        for (int e = 0; e < 4; ++e) {
            int c = (u >> (8 * e)) & 0xFF;
            int dl = c & 31;
            hs[(bo + e) * HROW + k] = (dl == 31) ? INF2 : (float)(dl * dl + kk);
        }
        flgw[m] = (u >> 7) & 0x01010101u;   // packed flags
    }
    __syncthreads();

    int w = t & 7, q = t >> 3;
    int i0 = q * 8;
    float best[8], neg2i[8], ifl[8];
#pragma unroll
    for (int j = 0; j < 8; ++j) {
        best[j] = BIG;
        ifl[j] = (float)(i0 + j);
        neg2i[j] = (float)(-2 * (i0 + j));
    }
    eval_minplus(&hs[w * HROW], q, best, neg2i, ifl);

    const unsigned char* flgb = reinterpret_cast<const unsigned char*>(flgw);
    float wgf = (float)(w0 + w);
    float* ob = out + (size_t)b * PLANE + w0 + w;
#pragma unroll
    for (int j = 0; j < 8; ++j) {
        float v = fmaf(ifl[j], ifl[j], best[j]);   // exact d^2 after B+H
        float v2 = fmaf(wgf, wgf, v);              // fold W-pass +k^2 (exact)
        unsigned int bits = __float_as_uint(v2) |
                            ((unsigned int)flgb[(i0 + j) * TWB + w] << 31);
        ob[(size_t)(i0 + j) * NW] = __uint_as_float(bits);
    }
}

// ---------------------------------------------------------------------------
// K3: min-plus along W, in-place on out, 8 lines/block, 1024 blocks.
// +k^2 pre-folded by K2; NaN flag in sign bit; sqrt + NaN epilogue.
// ---------------------------------------------------------------------------
__global__ __launch_bounds__(512, 4) void k_pass_w(float* __restrict__ out) {
    __shared__ float hs[TWB * HROW];
    __shared__ unsigned int flgw[NH * 2];
    int t = threadIdx.x;
    int line0 = blockIdx.x * TWB;
    float* gb = out + (size_t)line0 * NW;

    for (int m = t; m < 1024; m += 512) {
        float4 v = *reinterpret_cast<const float4*>(gb + (size_t)m * 4);
        int line = m >> 7;
        int k = (m * 4) & 511;
        unsigned int u0 = __float_as_uint(v.x), u1 = __float_as_uint(v.y);
        unsigned int u2 = __float_as_uint(v.z), u3 = __float_as_uint(v.w);
        flgw[m] = (u0 >> 31) | ((u1 >> 31) << 8) |
                  ((u2 >> 31) << 16) | ((u3 >> 31) << 24);
        float4 o;
        o.x = __uint_as_float(u0 & 0x7fffffffu);
        o.y = __uint_as_float(u1 & 0x7fffffffu);
        o.z = __uint_as_float(u2 & 0x7fffffffu);
        o.w = __uint_as_float(u3 & 0x7fffffffu);
        *reinterpret_cast<float4*>(&hs[line * HROW + k]) = o;
    }
    __syncthreads();

    int line = t & 7, q = t >> 3;
    int i0 = q * 8;
    float best[8], neg2i[8], ifl[8];
#pragma unroll
    for (int j = 0; j < 8; ++j) {
        best[j] = BIG;
        ifl[j] = (float)(i0 + j);
        neg2i[j] = (float)(-2 * (i0 + j));
    }
    eval_minplus(&hs[line * HROW], q, best, neg2i, ifl);

    unsigned int f0 = flgw[(line * NW + i0) >> 2];
    unsigned int f1 = flgw[((line * NW + i0) >> 2) + 1];
    float v[8];
#pragma unroll
    for (int j = 0; j < 8; ++j) {
        float m = fmaf(ifl[j], ifl[j], best[j]);  // exact final d^2
        float sq = sqrtf(m);
        unsigned int fb = (j < 4) ? ((f0 >> (8 * j)) & 1u)
                                  : ((f1 >> (8 * (j - 4))) & 1u);
        v[j] = fb ? __builtin_nanf("") : sq;
    }
    float* op = gb + (size_t)line * NW + i0;
    float4 oa, ob4;
    oa.x = v[0]; oa.y = v[1]; oa.z = v[2]; oa.w = v[3];
    ob4.x = v[4]; ob4.y = v[5]; ob4.z = v[6]; ob4.w = v[7];
    *reinterpret_cast<float4*>(op) = oa;
    *reinterpret_cast<float4*>(op + 4) = ob4;
}

extern "C" void kernel_launch(void* const* d_in, const int* in_sizes, int n_in,
                              void* d_out, int out_size, void* d_ws, size_t ws_size,
                              hipStream_t stream) {
    (void)in_sizes; (void)n_in; (void)out_size; (void)ws_size;
    const float* x = (const float*)d_in[0];
    float* out = (float*)d_out;
    unsigned char* code = (unsigned char*)d_ws;  // 4.2 MB u8 codes

    // K1: x -> u8 codes (d along B + NaN flag)
    k_pass_b<<<dim3(PLANE / 256), 256, 0, stream>>>(x, code);
    // K2: min-plus along H: codes -> out (+w^2 folded, NaN in sign bit)
    k_pass_h<<<dim3(NW / TWB, NB), 512, 0, stream>>>(code, out);
    // K3: min-plus along W, in-place on out, sqrt + NaN mask
    k_pass_w<<<dim3(NB * NH / TWB), 512, 0, stream>>>(out);
}